// Round 1
// baseline (6623.920 us; speedup 1.0000x reference)
//
#include <hip/hip_runtime.h>
#include <math.h>

#define N_NODES 100000
#define IN_DIM  512
#define HID     5
#define HEADS   5
#define C1      25   // HEADS*HID
#define NC      3
#define NEG     0.2f

__device__ __forceinline__ unsigned fenc(float f) {
    unsigned b = __float_as_uint(f);
    return (b & 0x80000000u) ? ~b : (b | 0x80000000u);
}
__device__ __forceinline__ float fdec(unsigned u) {
    return (u & 0x80000000u) ? __uint_as_float(u & 0x7FFFFFFFu) : __uint_as_float(~u);
}
__device__ __forceinline__ float lrelu(float v) { return v >= 0.f ? v : NEG * v; }

// ---- K1: h1 = x @ W1 (fused: per-head attention scalars) ----
__global__ void k_gemm1(const float* __restrict__ x, const float* __restrict__ W1,
                        const float* __restrict__ as1, const float* __restrict__ ad1,
                        float* __restrict__ h1p, float* __restrict__ asrc,
                        float* __restrict__ adst) {
    int n = blockIdx.x * blockDim.x + threadIdx.x;
    if (n >= N_NODES) return;
    const float4* xr = (const float4*)(x + (size_t)n * IN_DIM);
    float acc[C1];
#pragma unroll
    for (int j = 0; j < C1; ++j) acc[j] = 0.f;
    for (int k4 = 0; k4 < IN_DIM / 4; ++k4) {
        float4 xv = xr[k4];
        const float* wr = W1 + k4 * 4 * C1;   // rows 4k4..4k4+3, wave-uniform -> s_load
#pragma unroll
        for (int j = 0; j < C1; ++j)
            acc[j] += xv.x * wr[j] + xv.y * wr[C1 + j] + xv.z * wr[2 * C1 + j] + xv.w * wr[3 * C1 + j];
    }
    float* hrow = h1p + (size_t)n * 32;
#pragma unroll
    for (int j = 0; j < C1; ++j) hrow[j] = acc[j];
#pragma unroll
    for (int h = 0; h < HEADS; ++h) {
        float s = 0.f, d = 0.f;
#pragma unroll
        for (int c = 0; c < HID; ++c) {
            s += acc[h * HID + c] * as1[h * HID + c];
            d += acc[h * HID + c] * ad1[h * HID + c];
        }
        asrc[n * HEADS + h] = s;
        adst[n * HEADS + h] = d;
    }
}

// ---- K2: layer-1 per-dst max (segment_max via encoded atomicMax) ----
__global__ void k_edge1_max(const int* __restrict__ ei, int E,
                            const float* __restrict__ asrc, const float* __restrict__ adst,
                            unsigned* __restrict__ m1) {
    int e = blockIdx.x * blockDim.x + threadIdx.x;
    int tot = E + N_NODES;
    if (e >= tot) return;
    int s, d;
    if (e < E) { s = ei[e]; d = ei[E + e]; } else { s = d = e - E; }
#pragma unroll
    for (int h = 0; h < HEADS; ++h) {
        float v = lrelu(asrc[s * HEADS + h] + adst[d * HEADS + h]);
        atomicMax(&m1[d * HEADS + h], fenc(v));
    }
}

// ---- K3: layer-1 numerator+denominator accumulate ----
__global__ void k_edge1_acc(const int* __restrict__ ei, int E,
                            const float* __restrict__ asrc, const float* __restrict__ adst,
                            const unsigned* __restrict__ m1, const float* __restrict__ h1p,
                            float* __restrict__ denom, float* __restrict__ outnum) {
    int e = blockIdx.x * blockDim.x + threadIdx.x;
    int tot = E + N_NODES;
    if (e >= tot) return;
    int s, d;
    if (e < E) { s = ei[e]; d = ei[E + e]; } else { s = d = e - E; }
    float p[HEADS];
#pragma unroll
    for (int h = 0; h < HEADS; ++h) {
        float v = lrelu(asrc[s * HEADS + h] + adst[d * HEADS + h]);
        p[h] = expf(v - fdec(m1[d * HEADS + h]));
        atomicAdd(&denom[d * HEADS + h], p[h]);
    }
    const float4* hr = (const float4*)(h1p + (size_t)s * 32);
    float hv[28];
#pragma unroll
    for (int q = 0; q < 7; ++q) {
        float4 v = hr[q];
        hv[q * 4 + 0] = v.x; hv[q * 4 + 1] = v.y; hv[q * 4 + 2] = v.z; hv[q * 4 + 3] = v.w;
    }
    float* orow = outnum + (size_t)d * C1;
#pragma unroll
    for (int h = 0; h < HEADS; ++h)
#pragma unroll
        for (int c = 0; c < HID; ++c)
            atomicAdd(&orow[h * HID + c], p[h] * hv[h * HID + c]);
}

// ---- K4: normalize + bias + ELU + g = h2@W2 + layer-2 attention scalars ----
__global__ void k_node1(const float* __restrict__ outnum, const float* __restrict__ denom,
                        const float* __restrict__ b1, const float* __restrict__ W2,
                        const float* __restrict__ as2, const float* __restrict__ ad2,
                        float* __restrict__ g, float* __restrict__ a2s, float* __restrict__ a2d) {
    int n = blockIdx.x * blockDim.x + threadIdx.x;
    if (n >= N_NODES) return;
    float h2[C1];
#pragma unroll
    for (int h = 0; h < HEADS; ++h) {
        float inv = 1.f / denom[n * HEADS + h];
#pragma unroll
        for (int c = 0; c < HID; ++c) {
            float v = outnum[(size_t)n * C1 + h * HID + c] * inv + b1[h * HID + c];
            h2[h * HID + c] = v > 0.f ? v : expm1f(v);
        }
    }
    float gg[NC];
#pragma unroll
    for (int c = 0; c < NC; ++c) gg[c] = 0.f;
#pragma unroll
    for (int j = 0; j < C1; ++j)
#pragma unroll
        for (int c = 0; c < NC; ++c) gg[c] += h2[j] * W2[j * NC + c];
    float ss = 0.f, dd = 0.f;
#pragma unroll
    for (int c = 0; c < NC; ++c) {
        g[n * 4 + c] = gg[c];
        ss += gg[c] * as2[c];
        dd += gg[c] * ad2[c];
    }
    a2s[n] = ss;
    a2d[n] = dd;
}

// ---- K5: layer-2 per-dst max ----
__global__ void k_edge2_max(const int* __restrict__ ei, int E,
                            const float* __restrict__ a2s, const float* __restrict__ a2d,
                            unsigned* __restrict__ m2) {
    int e = blockIdx.x * blockDim.x + threadIdx.x;
    int tot = E + N_NODES;
    if (e >= tot) return;
    int s, d;
    if (e < E) { s = ei[e]; d = ei[E + e]; } else { s = d = e - E; }
    float v = lrelu(a2s[s] + a2d[d]);
    atomicMax(&m2[d], fenc(v));
}

// ---- K6: layer-2 accumulate ----
__global__ void k_edge2_acc(const int* __restrict__ ei, int E,
                            const float* __restrict__ a2s, const float* __restrict__ a2d,
                            const unsigned* __restrict__ m2, const float* __restrict__ g,
                            float* __restrict__ denom2, float* __restrict__ out2n) {
    int e = blockIdx.x * blockDim.x + threadIdx.x;
    int tot = E + N_NODES;
    if (e >= tot) return;
    int s, d;
    if (e < E) { s = ei[e]; d = ei[E + e]; } else { s = d = e - E; }
    float v = lrelu(a2s[s] + a2d[d]);
    float p = expf(v - fdec(m2[d]));
    atomicAdd(&denom2[d], p);
#pragma unroll
    for (int c = 0; c < NC; ++c)
        atomicAdd(&out2n[(size_t)d * NC + c], p * g[s * 4 + c]);
}

// ---- K7: final log_sigmoid ----
__global__ void k_final(const float* __restrict__ out2n, const float* __restrict__ denom2,
                        const float* __restrict__ b2, float* __restrict__ out) {
    int i = blockIdx.x * blockDim.x + threadIdx.x;
    if (i >= N_NODES * NC) return;
    int n = i / NC, c = i % NC;
    float v = out2n[i] / denom2[n] + b2[c];
    float ls = (v >= 0.f) ? -log1pf(expf(-v)) : v - log1pf(expf(v));
    out[i] = ls;
}

extern "C" void kernel_launch(void* const* d_in, const int* in_sizes, int n_in,
                              void* d_out, int out_size, void* d_ws, size_t ws_size,
                              hipStream_t stream) {
    const float* x   = (const float*)d_in[0];
    const int*   ei  = (const int*)d_in[1];
    const float* W1  = (const float*)d_in[2];
    const float* as1 = (const float*)d_in[3];
    const float* ad1 = (const float*)d_in[4];
    const float* b1  = (const float*)d_in[5];
    const float* W2  = (const float*)d_in[6];
    const float* as2 = (const float*)d_in[7];
    const float* ad2 = (const float*)d_in[8];
    const float* b2  = (const float*)d_in[9];
    float* out = (float*)d_out;
    int E = in_sizes[1] / 2;
    int TOT = E + N_NODES;

    float* ws = (float*)d_ws;
    // zero-region (memset every launch): [0 .. 4,000,000)
    unsigned* m1    = (unsigned*)ws;          // N*5
    float* denom1   = ws + 500000;            // N*5
    float* out1n    = ws + 1000000;           // N*25
    unsigned* m2    = (unsigned*)(ws + 3500000); // N
    float* denom2   = ws + 3600000;           // N
    float* out2n    = ws + 3700000;           // N*3
    // non-zeroed scratch
    float* h1p      = ws + 4000000;           // N*32 (25 used, padded for float4)
    float* asrc1    = ws + 7200000;           // N*5
    float* adst1    = ws + 7700000;           // N*5
    float* g        = ws + 8200000;           // N*4 (3 used)
    float* a2s      = ws + 8600000;           // N
    float* a2d      = ws + 8700000;           // N  (end: 8,800,000 floats = 35.2 MB)

    hipMemsetAsync(d_ws, 0, 4000000 * sizeof(float), stream);

    dim3 blk(256);
    k_gemm1<<<dim3((N_NODES + 255) / 256), blk, 0, stream>>>(x, W1, as1, ad1, h1p, asrc1, adst1);
    k_edge1_max<<<dim3((TOT + 255) / 256), blk, 0, stream>>>(ei, E, asrc1, adst1, m1);
    k_edge1_acc<<<dim3((TOT + 255) / 256), blk, 0, stream>>>(ei, E, asrc1, adst1, m1, h1p, denom1, out1n);
    k_node1<<<dim3((N_NODES + 255) / 256), blk, 0, stream>>>(out1n, denom1, b1, W2, as2, ad2, g, a2s, a2d);
    k_edge2_max<<<dim3((TOT + 255) / 256), blk, 0, stream>>>(ei, E, a2s, a2d, m2);
    k_edge2_acc<<<dim3((TOT + 255) / 256), blk, 0, stream>>>(ei, E, a2s, a2d, m2, g, denom2, out2n);
    k_final<<<dim3((N_NODES * NC + 255) / 256), blk, 0, stream>>>(out2n, denom2, b2, out);
}

// Round 2
// 776.207 us; speedup vs baseline: 8.5337x; 8.5337x over previous
//
#include <hip/hip_runtime.h>
#include <math.h>

#define N_NODES 100000
#define IN_DIM  512
#define HID     5
#define HEADS   5
#define C1      25   // HEADS*HID
#define NC      3
#define NEG     0.2f
#define NPB     64   // nodes per block in k_layer1

__device__ __forceinline__ float lrelu(float v) { return v >= 0.f ? v : NEG * v; }

// ---- K1: h1 = x @ W1 (fused: per-head attention scalars). h1p stride 28. ----
__global__ void k_gemm1(const float* __restrict__ x, const float* __restrict__ W1,
                        const float* __restrict__ as1, const float* __restrict__ ad1,
                        float* __restrict__ h1p, float* __restrict__ asrc,
                        float* __restrict__ adst) {
    int n = blockIdx.x * blockDim.x + threadIdx.x;
    if (n >= N_NODES) return;
    const float4* xr = (const float4*)(x + (size_t)n * IN_DIM);
    float acc[C1];
#pragma unroll
    for (int j = 0; j < C1; ++j) acc[j] = 0.f;
    for (int k4 = 0; k4 < IN_DIM / 4; ++k4) {
        float4 xv = xr[k4];
        const float* wr = W1 + k4 * 4 * C1;   // wave-uniform -> scalar loads
#pragma unroll
        for (int j = 0; j < C1; ++j)
            acc[j] += xv.x * wr[j] + xv.y * wr[C1 + j] + xv.z * wr[2 * C1 + j] + xv.w * wr[3 * C1 + j];
    }
    float* hrow = h1p + (size_t)n * 28;
#pragma unroll
    for (int j = 0; j < C1; ++j) hrow[j] = acc[j];
#pragma unroll
    for (int h = 0; h < HEADS; ++h) {
        float s = 0.f, d = 0.f;
#pragma unroll
        for (int c = 0; c < HID; ++c) {
            s += acc[h * HID + c] * as1[h * HID + c];
            d += acc[h * HID + c] * ad1[h * HID + c];
        }
        asrc[n * HEADS + h] = s;
        adst[n * HEADS + h] = d;
    }
}

// ---- CSR build: histogram of dst ----
__global__ void k_deg(const int* __restrict__ ei, int E, int* __restrict__ deg) {
    int e = blockIdx.x * blockDim.x + threadIdx.x;
    int tot = E + N_NODES;
    if (e >= tot) return;
    int d = (e < E) ? ei[E + e] : e - E;
    atomicAdd(&deg[d], 1);
}

// ---- exclusive scan (3 kernels) ----
__global__ void k_scan1(const int* __restrict__ deg, int* __restrict__ off, int* __restrict__ bsum) {
    __shared__ int sh[256];
    int i = blockIdx.x * 256 + threadIdx.x;
    int v = (i < N_NODES) ? deg[i] : 0;
    sh[threadIdx.x] = v;
    __syncthreads();
    for (int ofs = 1; ofs < 256; ofs <<= 1) {
        int t = (threadIdx.x >= ofs) ? sh[threadIdx.x - ofs] : 0;
        __syncthreads();
        sh[threadIdx.x] += t;
        __syncthreads();
    }
    if (i < N_NODES) off[i] = sh[threadIdx.x] - v;   // exclusive within block
    if (threadIdx.x == 255) bsum[blockIdx.x] = sh[255];
}

__global__ void k_scan2(int* __restrict__ bsum, int nb) {
    if (blockIdx.x == 0 && threadIdx.x == 0) {
        int run = 0;
        for (int j = 0; j < nb; ++j) { int t = bsum[j]; bsum[j] = run; run += t; }
    }
}

__global__ void k_scan3(int* __restrict__ off, const int* __restrict__ bsum) {
    int i = blockIdx.x * 256 + threadIdx.x;
    if (i < N_NODES) off[i] += bsum[blockIdx.x];
}

// ---- scatter edges into CSR (src values grouped by dst) ----
__global__ void k_scatter(const int* __restrict__ ei, int E, const int* __restrict__ off,
                          int* __restrict__ cur, int* __restrict__ ssrc) {
    int e = blockIdx.x * blockDim.x + threadIdx.x;
    int tot = E + N_NODES;
    if (e >= tot) return;
    int s, d;
    if (e < E) { s = ei[e]; d = ei[E + e]; } else { s = d = e - E; }
    int pos = off[d] + atomicAdd(&cur[d], 1);
    ssrc[pos] = s;
}

// ---- Layer 1: per-(dst,head) segment softmax + aggregate; fused bias+ELU+W2+attn2 ----
__global__ void __launch_bounds__(NPB * HEADS)
k_layer1(const int* __restrict__ off, const int* __restrict__ deg, const int* __restrict__ ssrc,
         const float* __restrict__ asrc, const float* __restrict__ adst,
         const float* __restrict__ h1p, const float* __restrict__ b1,
         const float* __restrict__ W2, const float* __restrict__ as2, const float* __restrict__ ad2,
         float* __restrict__ g, float* __restrict__ a2s, float* __restrict__ a2d) {
    __shared__ float sh[NPB * C1];
    int tid = threadIdx.x;            // 0..319
    int ln = tid / HEADS, h = tid % HEADS;
    int n = blockIdx.x * NPB + ln;
    if (n < N_NODES) {
        int st = off[n], cnt = deg[n];
        float adn = adst[n * HEADS + h];
        float m = -1e30f;
        for (int i = 0; i < cnt; ++i) {
            int s = ssrc[st + i];
            m = fmaxf(m, lrelu(asrc[s * HEADS + h] + adn));
        }
        float num[HID] = {0.f, 0.f, 0.f, 0.f, 0.f};
        float den = 0.f;
        for (int i = 0; i < cnt; ++i) {
            int s = ssrc[st + i];
            float v = lrelu(asrc[s * HEADS + h] + adn);
            float p = __expf(v - m);
            den += p;
            const float* hr = h1p + (size_t)s * 28 + h * HID;
#pragma unroll
            for (int c = 0; c < HID; ++c) num[c] += p * hr[c];
        }
        float inv = 1.f / den;
#pragma unroll
        for (int c = 0; c < HID; ++c) {
            float v = num[c] * inv + b1[h * HID + c];
            sh[ln * C1 + h * HID + c] = v > 0.f ? v : expm1f(v);
        }
    }
    __syncthreads();
    if (tid < NPB) {
        int n2 = blockIdx.x * NPB + tid;
        if (n2 < N_NODES) {
            float gg[NC] = {0.f, 0.f, 0.f};
#pragma unroll
            for (int j = 0; j < C1; ++j) {
                float hv = sh[tid * C1 + j];
#pragma unroll
                for (int c = 0; c < NC; ++c) gg[c] += hv * W2[j * NC + c];
            }
            float ssv = 0.f, ddv = 0.f;
#pragma unroll
            for (int c = 0; c < NC; ++c) {
                g[n2 * 4 + c] = gg[c];
                ssv += gg[c] * as2[c];
                ddv += gg[c] * ad2[c];
            }
            a2s[n2] = ssv;
            a2d[n2] = ddv;
        }
    }
}

// ---- Layer 2: per-dst segment softmax + aggregate + log_sigmoid ----
__global__ void k_layer2(const int* __restrict__ off, const int* __restrict__ deg,
                         const int* __restrict__ ssrc,
                         const float* __restrict__ a2s, const float* __restrict__ a2d,
                         const float* __restrict__ g, const float* __restrict__ b2,
                         float* __restrict__ out) {
    int n = blockIdx.x * blockDim.x + threadIdx.x;
    if (n >= N_NODES) return;
    int st = off[n], cnt = deg[n];
    float adn = a2d[n];
    float m = -1e30f;
    for (int i = 0; i < cnt; ++i) {
        int s = ssrc[st + i];
        m = fmaxf(m, lrelu(a2s[s] + adn));
    }
    float num0 = 0.f, num1 = 0.f, num2 = 0.f, den = 0.f;
    for (int i = 0; i < cnt; ++i) {
        int s = ssrc[st + i];
        float p = __expf(lrelu(a2s[s] + adn) - m);
        den += p;
        float4 gv = *(const float4*)(g + (size_t)s * 4);
        num0 += p * gv.x; num1 += p * gv.y; num2 += p * gv.z;
    }
    float inv = 1.f / den;
    float vv[NC] = {num0 * inv + b2[0], num1 * inv + b2[1], num2 * inv + b2[2]};
#pragma unroll
    for (int c = 0; c < NC; ++c) {
        float v = vv[c];
        out[n * NC + c] = (v >= 0.f) ? -log1pf(__expf(-v)) : v - log1pf(__expf(v));
    }
}

extern "C" void kernel_launch(void* const* d_in, const int* in_sizes, int n_in,
                              void* d_out, int out_size, void* d_ws, size_t ws_size,
                              hipStream_t stream) {
    const float* x   = (const float*)d_in[0];
    const int*   ei  = (const int*)d_in[1];
    const float* W1  = (const float*)d_in[2];
    const float* as1 = (const float*)d_in[3];
    const float* ad1 = (const float*)d_in[4];
    const float* b1  = (const float*)d_in[5];
    const float* W2  = (const float*)d_in[6];
    const float* as2 = (const float*)d_in[7];
    const float* ad2 = (const float*)d_in[8];
    const float* b2  = (const float*)d_in[9];
    float* out = (float*)d_out;
    int E = in_sizes[1] / 2;
    int TOT = E + N_NODES;

    int*   iws = (int*)d_ws;
    float* fws = (float*)d_ws;
    // zero-region: first 200,000 ints (deg + cur)
    int* deg    = iws;            // N
    int* cur    = iws + 100000;   // N
    int* off    = iws + 200000;   // N
    int* bsum   = iws + 300000;   // 1024
    int* ssrc   = iws + 301024;   // TOT (<= 3,300,000) -> 3,601,024
    float* h1p  = fws + 3601024;  // N*28 -> 6,401,024
    float* asrc = fws + 6401024;  // N*5  -> 6,901,024
    float* adst = fws + 6901024;  // N*5  -> 7,401,024
    float* g    = fws + 7401024;  // N*4  -> 7,801,024
    float* a2s  = fws + 7801024;  // N
    float* a2d  = fws + 7901024;  // N -> 8,001,024 floats = 32 MB

    hipMemsetAsync(d_ws, 0, 200000 * sizeof(int), stream);

    dim3 blk(256);
    int NB1 = (N_NODES + 255) / 256;  // 391
    k_gemm1<<<dim3(NB1), blk, 0, stream>>>(x, W1, as1, ad1, h1p, asrc, adst);
    k_deg<<<dim3((TOT + 255) / 256), blk, 0, stream>>>(ei, E, deg);
    k_scan1<<<dim3(NB1), blk, 0, stream>>>(deg, off, bsum);
    k_scan2<<<dim3(1), blk, 0, stream>>>(bsum, NB1);
    k_scan3<<<dim3(NB1), blk, 0, stream>>>(off, bsum);
    k_scatter<<<dim3((TOT + 255) / 256), blk, 0, stream>>>(ei, E, off, cur, ssrc);
    k_layer1<<<dim3((N_NODES + NPB - 1) / NPB), dim3(NPB * HEADS), 0, stream>>>(
        off, deg, ssrc, asrc, adst, h1p, b1, W2, as2, ad2, g, a2s, a2d);
    k_layer2<<<dim3(NB1), blk, 0, stream>>>(off, deg, ssrc, a2s, a2d, g, b2, out);
}